// Round 6
// baseline (393.857 us; speedup 1.0000x reference)
//
#include <hip/hip_runtime.h>
#include <hip/hip_bf16.h>
#include <stdint.h>

using bf16   = __hip_bfloat16;
using bf16x8 = __attribute__((ext_vector_type(8))) short;
using bf16x4 = __attribute__((ext_vector_type(4))) short;
using f32x4  = __attribute__((ext_vector_type(4))) float;
using f32x4a = __attribute__((ext_vector_type(4), aligned(4))) float;

// async global->LDS, 16B/lane. LDS dest must be wave-uniform; HW adds lane*16.
__device__ __forceinline__ void g2l16(const void* g, void* l) {
  __builtin_amdgcn_global_load_lds(
      (const __attribute__((address_space(1))) void*)g,
      (__attribute__((address_space(3))) void*)l, 16, 0, 0);
}

// ---- load 8 contiguous f32 -> bf16x8 ----
__device__ __forceinline__ bf16x8 load8(const float* p) {
  f32x4 a = *(const f32x4*)p;
  f32x4 b = *(const f32x4*)(p + 4);
  bf16x8 r;
  bf16* rp = (bf16*)&r;
#pragma unroll
  for (int j = 0; j < 4; ++j) rp[j]     = __float2bfloat16(a[j]);
#pragma unroll
  for (int j = 0; j < 4; ++j) rp[4 + j] = __float2bfloat16(b[j]);
  return r;
}

// ---------------- fused prep: cvt q/k/v (z=0..2), transpose W (z=3..6), bias (z=7) ----
__global__ __launch_bounds__(256)
void prep(const float* __restrict__ q, const float* __restrict__ k,
          const float* __restrict__ v,
          bf16* __restrict__ oq, bf16* __restrict__ ok, bf16* __restrict__ ov,
          const float* __restrict__ Wq, const float* __restrict__ Wk,
          const float* __restrict__ Wv, const float* __restrict__ Wo,
          bf16* __restrict__ WqT, bf16* __restrict__ WkT,
          bf16* __restrict__ WvT, bf16* __restrict__ WoT,
          const float* __restrict__ rpe, float* __restrict__ bt)
{
  const int z = blockIdx.z, x = blockIdx.x, tid = threadIdx.x;
  if (z < 3) {
    const float* src = (z == 0) ? q : (z == 1) ? k : v;
    bf16* dst        = (z == 0) ? oq : (z == 1) ? ok : ov;
    const int i = (x * 256 + tid) * 8;
    *(bf16x8*)(dst + i) = load8(src + i);
  } else if (z < 7) {
    if (x >= 1024) return;
    __shared__ float tile[32][33];
    const float* in = (z == 3) ? Wq : (z == 4) ? Wk : (z == 5) ? Wv : Wo;
    bf16* out       = (z == 3) ? WqT : (z == 4) ? WkT : (z == 5) ? WvT : WoT;
    const int bx = (x & 31) * 32, by = (x >> 5) * 32;
    const int tx = tid & 31, ty = tid >> 5;
#pragma unroll
    for (int i = 0; i < 4; ++i)
      tile[ty + i * 8][tx] = in[(size_t)(by + ty + i * 8) * 1024 + bx + tx];
    __syncthreads();
#pragma unroll
    for (int i = 0; i < 4; ++i)
      out[(size_t)(bx + ty + i * 8) * 1024 + by + tx] =
          __float2bfloat16(tile[tx][ty + i * 8]);
  } else {
    const int idx = x * 256 + tid;
    if (idx >= 16 * 4104) return;
    const int h = idx / 4104, j = idx - h * 4104;
    const int d = j - 3;
    float val = 0.f;
    if (d >= 0 && d < 4096) {
      int b;
      if (d < 16) {
        b = d;
      } else {
        const int T[15] = {23, 32, 46, 64, 91, 128, 182, 256, 363, 512,
                           725, 1024, 1449, 2048, 2897};
        int m = 0;
#pragma unroll
        for (int i = 0; i < 15; ++i) m += (d >= T[i]);
        b = 16 + m;
      }
      val = rpe[b * 16 + h] * 1.4426950408889634f;
    }
    bt[idx] = val;
  }
}

// ---------------- GEMM: C[4096,1024] = A @ W + bias (Wt = W^T, both bf16) ----------
// 128xBN tile, BK=64, 4 waves (2x2). global_load_lds width-16 staging:
// linear LDS dest + inverse-swizzled global source; swizzled ds_read.
template <typename OT, int BN>
__device__ __forceinline__ void gemm_body(const bf16* __restrict__ A,
                                          const bf16* __restrict__ Wt,
                                          const float* __restrict__ bias,
                                          OT* __restrict__ C, bool vt,
                                          bf16* As, bf16* Bs)
{
  constexpr int NF = BN / 32;            // N-frags per wave
  const int tid = threadIdx.x;
  const int lane = tid & 63, wid = tid >> 6;
  const int l15 = lane & 15, lg = lane >> 4;
  const int wr = wid >> 1, wc = wid & 1;
  const int m0 = blockIdx.x * 128, n0 = blockIdx.y * BN;

  f32x4 acc[4][NF];
#pragma unroll
  for (int i = 0; i < 4; ++i)
#pragma unroll
    for (int j = 0; j < NF; ++j) acc[i][j] = (f32x4){0.f, 0.f, 0.f, 0.f};

#pragma unroll 1
  for (int kt = 0; kt < 16; ++kt) {
    const int k0 = kt * 64;
    __syncthreads();
#pragma unroll
    for (int it = 0; it < 4; ++it) {
      const int o = tid * 16 + it * 4096;
      const int row = o >> 7;
      const int sl = ((o >> 4) & 7) ^ (row & 7);
      g2l16(A + (size_t)(m0 + row) * 1024 + k0 + sl * 8,
            (char*)As + wid * 1024 + it * 4096);
    }
#pragma unroll
    for (int it = 0; it < BN / 32; ++it) {
      const int o = tid * 16 + it * 4096;
      const int row = o >> 7;
      const int sl = ((o >> 4) & 7) ^ (row & 7);
      g2l16(Wt + (size_t)(n0 + row) * 1024 + k0 + sl * 8,
            (char*)Bs + wid * 1024 + it * 4096);
    }
    __syncthreads();

    bf16x8 af[2][4], bfr[2][NF];
#pragma unroll
    for (int ks = 0; ks < 2; ++ks) {
      const int s8 = ks * 4 + lg;
#pragma unroll
      for (int f = 0; f < 4; ++f) {
        const int ra_ = wr * 64 + f * 16 + l15;
        af[ks][f] = *(const bf16x8*)((const char*)As + ra_ * 128 + ((s8 ^ (ra_ & 7)) << 4));
      }
#pragma unroll
      for (int f = 0; f < NF; ++f) {
        const int rb_ = wc * (BN / 2) + f * 16 + l15;
        bfr[ks][f] = *(const bf16x8*)((const char*)Bs + rb_ * 128 + ((s8 ^ (rb_ & 7)) << 4));
      }
    }
#pragma unroll
    for (int ks = 0; ks < 2; ++ks)
#pragma unroll
      for (int mf = 0; mf < 4; ++mf)
#pragma unroll
        for (int nf = 0; nf < NF; ++nf)
          acc[mf][nf] = __builtin_amdgcn_mfma_f32_16x16x32_bf16(
              af[ks][mf], bfr[ks][nf], acc[mf][nf], 0, 0, 0);
  }

#pragma unroll
  for (int nf = 0; nf < NF; ++nf) {
    const int col = n0 + wc * (BN / 2) + nf * 16 + l15;
    const float bv = bias[col];
#pragma unroll
    for (int mf = 0; mf < 4; ++mf) {
      const int rowb = m0 + wr * 64 + mf * 16 + lg * 4;
#pragma unroll
      for (int r = 0; r < 4; ++r) {
        const float val = acc[mf][nf][r] + bv;
        if constexpr (sizeof(OT) == 2) {
          if (vt)   // V stored transposed per head: C[h][d][row]
            ((bf16*)C)[((size_t)(col >> 6) << 18) + ((size_t)(col & 63) << 12) + rowb + r] =
                __float2bfloat16(val);
          else
            ((bf16*)C)[(size_t)(rowb + r) * 1024 + col] = __float2bfloat16(val);
        } else {
          ((float*)C)[(size_t)(rowb + r) * 1024 + col] = val;
        }
      }
    }
  }
}

__global__ __launch_bounds__(256)
void gemm_qkv(const bf16* __restrict__ xq, const bf16* __restrict__ xk,
              const bf16* __restrict__ xv,
              const bf16* __restrict__ wqt, const bf16* __restrict__ wkt,
              const bf16* __restrict__ wvt,
              const float* __restrict__ bq, const float* __restrict__ bk,
              const float* __restrict__ bv,
              bf16* __restrict__ Q, bf16* __restrict__ K, bf16* __restrict__ VtG)
{
  __shared__ bf16 As[128 * 64], Bs[128 * 64];
  const int z = blockIdx.z;
  gemm_body<bf16, 128>(z == 0 ? xq : z == 1 ? xk : xv,
                       z == 0 ? wqt : z == 1 ? wkt : wvt,
                       z == 0 ? bq : z == 1 ? bk : bv,
                       z == 0 ? Q : z == 1 ? K : VtG, z == 2, As, Bs);
}

__global__ __launch_bounds__(256)
void gemm_out_k(const bf16* __restrict__ A, const bf16* __restrict__ Wt,
                const float* __restrict__ bias, float* __restrict__ C)
{
  __shared__ bf16 As[128 * 64], Bs[64 * 64];
  gemm_body<float, 64>(A, Wt, bias, C, false, As, Bs);
}

// ---------------- causal flash attention + T5 bias (swapped QK^T) ----------------
// grid 512; bid -> (h = bid&15, qt = 31 - bid>>4). 4 waves x 32 q-rows = 128 q/block.
// KV tile 64, staged once and reused by both q-frags. log2-domain softmax, defer-max.
__global__ __launch_bounds__(256)
void attn_kernel(const bf16* __restrict__ Qb, const bf16* __restrict__ Kb,
                 const bf16* __restrict__ VtG, const float* __restrict__ bias_tab,
                 bf16* __restrict__ Ob)
{
  __shared__ bf16 Ks[64 * 64];
  __shared__ bf16 Vs[64 * 64];
  __shared__ bf16 Pl[4][32 * 76];

  const int tid = threadIdx.x;
  const int lane = tid & 63, wid = tid >> 6;
  const int l15 = lane & 15, lg = lane >> 4;
  const int bid = blockIdx.x;
  const int h  = bid & 15;
  const int qt = 31 - (bid >> 4);
  const int nt = 2 * qt + 2;
  const int qw = qt * 128 + wid * 32;
  const int q_abs0 = qw + l15;
  const int q_abs1 = qw + 16 + l15;
  const float C1 = 0.125f * 1.4426950408889634f;   // scale * log2(e)

  const bf16* Kh = Kb + h * 64;
  const bf16* Vh = VtG + ((size_t)h << 18);
  const float* bh = bias_tab + h * 4104 + 3;
  bf16* pw = &Pl[wid][0];

  const int kr0 = tid >> 3, ks0_ = tid & 7;
  const int kr1 = (tid + 256) >> 3, ks1_ = tid & 7;

  bf16x8 qf[2][2];
#pragma unroll
  for (int qi = 0; qi < 2; ++qi) {
    const bf16* qp = Qb + (size_t)(qw + qi * 16 + l15) * 1024 + h * 64 + lg * 8;
    qf[qi][0] = *(const bf16x8*)qp;
    qf[qi][1] = *(const bf16x8*)(qp + 32);
  }

  f32x4 o_acc[2][4];
#pragma unroll
  for (int qi = 0; qi < 2; ++qi)
#pragma unroll
    for (int nf = 0; nf < 4; ++nf) o_acc[qi][nf] = (f32x4){0.f, 0.f, 0.f, 0.f};
  float m_run[2] = {-1e30f, -1e30f};
  float l_run[2] = {0.f, 0.f};

  // prologue: load tile 0 into regs
  bf16x8 rk0 = *(const bf16x8*)(Kh + (size_t)kr0 * 1024 + ks0_ * 8);
  bf16x8 rk1 = *(const bf16x8*)(Kh + (size_t)kr1 * 1024 + ks1_ * 8);
  bf16x8 rv0 = *(const bf16x8*)(Vh + (size_t)kr0 * 4096 + ks0_ * 8);
  bf16x8 rv1 = *(const bf16x8*)(Vh + (size_t)kr1 * 4096 + ks1_ * 8);

#pragma unroll 1
  for (int t = 0; t < nt; ++t) {
    const int k0 = t * 64;
    __syncthreads();
    {
      const int o0 = kr0 * 128 + ((ks0_ ^ (kr0 & 7)) << 4);
      const int o1 = kr1 * 128 + ((ks1_ ^ (kr1 & 7)) << 4);
      *(bf16x8*)((char*)Ks + o0) = rk0;
      *(bf16x8*)((char*)Ks + o1) = rk1;
      *(bf16x8*)((char*)Vs + o0) = rv0;
      *(bf16x8*)((char*)Vs + o1) = rv1;
    }
    __syncthreads();
    if (t + 1 < nt) {   // T14: issue next tile's loads early
      const int k1 = k0 + 64;
      rk0 = *(const bf16x8*)(Kh + (size_t)(k1 + kr0) * 1024 + ks0_ * 8);
      rk1 = *(const bf16x8*)(Kh + (size_t)(k1 + kr1) * 1024 + ks1_ * 8);
      rv0 = *(const bf16x8*)(Vh + (size_t)kr0 * 4096 + k1 + ks0_ * 8);
      rv1 = *(const bf16x8*)(Vh + (size_t)kr1 * 4096 + k1 + ks1_ * 8);
    }

    // S^T = K . Q^T : lane holds S[q = l15-col][k = k0 + kf*16 + lg*4 + r]
    f32x4 st[2][4];
#pragma unroll
    for (int qi = 0; qi < 2; ++qi)
#pragma unroll
      for (int kf = 0; kf < 4; ++kf) st[qi][kf] = (f32x4){0.f, 0.f, 0.f, 0.f};
    __builtin_amdgcn_s_setprio(1);
#pragma unroll
    for (int kf = 0; kf < 4; ++kf) {
      const int row = kf * 16 + l15;
#pragma unroll
      for (int ks = 0; ks < 2; ++ks) {
        const int s8 = ks * 4 + lg;
        bf16x8 kfr = *(const bf16x8*)((const char*)Ks + row * 128 + ((s8 ^ (row & 7)) << 4));
        st[0][kf] = __builtin_amdgcn_mfma_f32_16x16x32_bf16(kfr, qf[0][ks], st[0][kf], 0, 0, 0);
        st[1][kf] = __builtin_amdgcn_mfma_f32_16x16x32_bf16(kfr, qf[1][ks], st[1][kf], 0, 0, 0);
      }
    }
    __builtin_amdgcn_s_setprio(0);

    // bias (vectorized, log2-domain) + mask + per-row max
    float mt[2] = {-1e30f, -1e30f};
#pragma unroll
    for (int qi = 0; qi < 2; ++qi) {
      const int qa = qi ? q_abs1 : q_abs0;
#pragma unroll
      for (int kf = 0; kf < 4; ++kf) {
        const int dtop = qa - (k0 + kf * 16 + lg * 4);
        f32x4a b4 = (f32x4a){0.f, 0.f, 0.f, 0.f};
        if (dtop >= 0) b4 = *(const f32x4a*)(bh + dtop - 3);
#pragma unroll
        for (int r = 0; r < 4; ++r) {
          const float bb = (dtop - r >= 0) ? b4[3 - r] : -1e30f;
          const float sv = st[qi][kf][r] * C1 + bb;
          st[qi][kf][r] = sv;
          mt[qi] = fmaxf(mt[qi], sv);
        }
      }
    }
    {
      float a0 = __shfl_xor(mt[0], 16, 64), a1 = __shfl_xor(mt[1], 16, 64);
      mt[0] = fmaxf(mt[0], a0); mt[1] = fmaxf(mt[1], a1);
      a0 = __shfl_xor(mt[0], 32, 64); a1 = __shfl_xor(mt[1], 32, 64);
      mt[0] = fmaxf(mt[0], a0); mt[1] = fmaxf(mt[1], a1);
    }

    // T13 defer-max: only rescale when tile max beats running max by >11 (log2)
#pragma unroll
    for (int qi = 0; qi < 2; ++qi) {
      if (__any(mt[qi] > m_run[qi] + 11.0f)) {
        const float newm = fmaxf(m_run[qi], mt[qi]);
        const float sc = (m_run[qi] > -1e29f) ? exp2f(m_run[qi] - newm) : 0.f;
        m_run[qi] = newm;
        float scr[4];
#pragma unroll
        for (int r = 0; r < 4; ++r) scr[r] = __shfl(sc, lg * 4 + r, 64);
#pragma unroll
        for (int nf = 0; nf < 4; ++nf)
#pragma unroll
          for (int r = 0; r < 4; ++r) o_acc[qi][nf][r] *= scr[r];
        l_run[qi] *= sc;
      }
    }

#pragma unroll
    for (int qi = 0; qi < 2; ++qi) {
      float rs = 0.f;
      bf16x4 pk[4];
#pragma unroll
      for (int kf = 0; kf < 4; ++kf)
#pragma unroll
        for (int r = 0; r < 4; ++r) {
          const float p = (st[qi][kf][r] > -1e29f) ? exp2f(st[qi][kf][r] - m_run[qi]) : 0.f;
          ((bf16*)&pk[kf])[r] = __float2bfloat16(p);
          rs += p;
        }
      rs += __shfl_xor(rs, 16, 64);
      rs += __shfl_xor(rs, 32, 64);
      l_run[qi] += rs;
#pragma unroll
      for (int kf = 0; kf < 4; ++kf)
        *(bf16x4*)&pw[(qi * 16 + l15) * 76 + kf * 16 + lg * 4] = pk[kf];
    }

    // PV: A = P (q rows), B = V^T-staged (d cols, k contiguous); Vs reads shared by qi
    bf16x8 pf[2][2];
#pragma unroll
    for (int qi = 0; qi < 2; ++qi)
#pragma unroll
      for (int ks2 = 0; ks2 < 2; ++ks2)
        pf[qi][ks2] = *(const bf16x8*)&pw[(qi * 16 + l15) * 76 + ks2 * 32 + lg * 8];
    __builtin_amdgcn_s_setprio(1);
#pragma unroll
    for (int ks2 = 0; ks2 < 2; ++ks2)
#pragma unroll
      for (int nf = 0; nf < 4; ++nf) {
        const int row = nf * 16 + l15;
        const int s8 = ks2 * 4 + lg;
        bf16x8 vfr = *(const bf16x8*)((const char*)Vs + row * 128 + ((s8 ^ (row & 7)) << 4));
        o_acc[0][nf] = __builtin_amdgcn_mfma_f32_16x16x32_bf16(pf[0][ks2], vfr, o_acc[0][nf], 0, 0, 0);
        o_acc[1][nf] = __builtin_amdgcn_mfma_f32_16x16x32_bf16(pf[1][ks2], vfr, o_acc[1][nf], 0, 0, 0);
      }
    __builtin_amdgcn_s_setprio(0);
  }

  // epilogue: O / l, store [S, H*64]
#pragma unroll
  for (int qi = 0; qi < 2; ++qi) {
    const float linv = 1.f / l_run[qi];
    float lr[4];
#pragma unroll
    for (int r = 0; r < 4; ++r) lr[r] = __shfl(linv, lg * 4 + r, 64);
#pragma unroll
    for (int nf = 0; nf < 4; ++nf)
#pragma unroll
      for (int r = 0; r < 4; ++r) {
        const int row = qw + qi * 16 + lg * 4 + r;
        Ob[(size_t)row * 1024 + h * 64 + nf * 16 + l15] =
            __float2bfloat16(o_acc[qi][nf][r] * lr[r]);
      }
  }
}

// ---------------- launch ----------------
extern "C" void kernel_launch(void* const* d_in, const int* in_sizes, int n_in,
                              void* d_out, int out_size, void* d_ws, size_t ws_size,
                              hipStream_t stream) {
  (void)in_sizes; (void)n_in; (void)out_size; (void)ws_size;
  const float* q   = (const float*)d_in[0];
  const float* k   = (const float*)d_in[1];
  const float* v   = (const float*)d_in[2];
  // d_in[3] = causal mask, deterministic -> ignored
  const float* Wq  = (const float*)d_in[4];
  const float* bq  = (const float*)d_in[5];
  const float* Wk  = (const float*)d_in[6];
  const float* bk  = (const float*)d_in[7];
  const float* Wv  = (const float*)d_in[8];
  const float* bv  = (const float*)d_in[9];
  const float* Wo  = (const float*)d_in[10];
  const float* bo  = (const float*)d_in[11];
  const float* rpe = (const float*)d_in[12];
  float* out = (float*)d_out;

  char* ws = (char*)d_ws;
  bf16* WqT   = (bf16*)(ws + (size_t)0);
  bf16* WkT   = (bf16*)(ws + ((size_t)2  << 20));
  bf16* WvT   = (bf16*)(ws + ((size_t)4  << 20));
  bf16* WoT   = (bf16*)(ws + ((size_t)6  << 20));
  bf16* xq_bf = (bf16*)(ws + ((size_t)8  << 20));
  bf16* xk_bf = (bf16*)(ws + ((size_t)16 << 20));
  bf16* xv_bf = (bf16*)(ws + ((size_t)24 << 20));
  bf16* Qb    = (bf16*)(ws + ((size_t)32 << 20));
  bf16* Kb    = (bf16*)(ws + ((size_t)40 << 20));
  bf16* VtG   = (bf16*)(ws + ((size_t)48 << 20));   // [16][64][4096]
  float* bias_tab = (float*)(ws + ((size_t)56 << 20));
  bf16* Ob    = xq_bf;   // xq_bf dead after gemm_qkv; reuse for attn output

  prep<<<dim3(2048, 1, 8), 256, 0, stream>>>(q, k, v, xq_bf, xk_bf, xv_bf,
                                             Wq, Wk, Wv, Wo, WqT, WkT, WvT, WoT,
                                             rpe, bias_tab);
  gemm_qkv<<<dim3(32, 8, 3), 256, 0, stream>>>(xq_bf, xk_bf, xv_bf, WqT, WkT, WvT,
                                               bq, bk, bv, Qb, Kb, VtG);
  attn_kernel<<<dim3(512), 256, 0, stream>>>(Qb, Kb, VtG, bias_tab, Ob);
  gemm_out_k<<<dim3(32, 16), 256, 0, stream>>>(Ob, WoT, bo, out);
}

// Round 7
// 344.182 us; speedup vs baseline: 1.1443x; 1.1443x over previous
//
#include <hip/hip_runtime.h>
#include <hip/hip_bf16.h>
#include <stdint.h>

using bf16   = __hip_bfloat16;
using bf16x8 = __attribute__((ext_vector_type(8))) short;
using bf16x4 = __attribute__((ext_vector_type(4))) short;
using f32x4  = __attribute__((ext_vector_type(4))) float;
using f32x4a = __attribute__((ext_vector_type(4), aligned(4))) float;

// async global->LDS, 16B/lane. LDS dest must be wave-uniform; HW adds lane*16.
__device__ __forceinline__ void g2l16(const void* g, void* l) {
  __builtin_amdgcn_global_load_lds(
      (const __attribute__((address_space(1))) void*)g,
      (__attribute__((address_space(3))) void*)l, 16, 0, 0);
}

// ---- load 8 contiguous f32 -> bf16x8 ----
__device__ __forceinline__ bf16x8 load8(const float* p) {
  f32x4 a = *(const f32x4*)p;
  f32x4 b = *(const f32x4*)(p + 4);
  bf16x8 r;
  bf16* rp = (bf16*)&r;
#pragma unroll
  for (int j = 0; j < 4; ++j) rp[j]     = __float2bfloat16(a[j]);
#pragma unroll
  for (int j = 0; j < 4; ++j) rp[4 + j] = __float2bfloat16(b[j]);
  return r;
}

// ---------------- fused prep: cvt q/k/v (z=0..2), transpose W (z=3..6), bias (z=7) ----
__global__ __launch_bounds__(256)
void prep(const float* __restrict__ q, const float* __restrict__ k,
          const float* __restrict__ v,
          bf16* __restrict__ oq, bf16* __restrict__ ok, bf16* __restrict__ ov,
          const float* __restrict__ Wq, const float* __restrict__ Wk,
          const float* __restrict__ Wv, const float* __restrict__ Wo,
          bf16* __restrict__ WqT, bf16* __restrict__ WkT,
          bf16* __restrict__ WvT, bf16* __restrict__ WoT,
          const float* __restrict__ rpe, float* __restrict__ bt)
{
  const int z = blockIdx.z, x = blockIdx.x, tid = threadIdx.x;
  if (z < 3) {
    const float* src = (z == 0) ? q : (z == 1) ? k : v;
    bf16* dst        = (z == 0) ? oq : (z == 1) ? ok : ov;
    const int i = (x * 256 + tid) * 8;
    *(bf16x8*)(dst + i) = load8(src + i);
  } else if (z < 7) {
    if (x >= 1024) return;
    __shared__ float tile[32][33];
    const float* in = (z == 3) ? Wq : (z == 4) ? Wk : (z == 5) ? Wv : Wo;
    bf16* out       = (z == 3) ? WqT : (z == 4) ? WkT : (z == 5) ? WvT : WoT;
    const int bx = (x & 31) * 32, by = (x >> 5) * 32;
    const int tx = tid & 31, ty = tid >> 5;
#pragma unroll
    for (int i = 0; i < 4; ++i)
      tile[ty + i * 8][tx] = in[(size_t)(by + ty + i * 8) * 1024 + bx + tx];
    __syncthreads();
#pragma unroll
    for (int i = 0; i < 4; ++i)
      out[(size_t)(bx + ty + i * 8) * 1024 + by + tx] =
          __float2bfloat16(tile[tx][ty + i * 8]);
  } else {
    const int idx = x * 256 + tid;
    if (idx >= 16 * 4104) return;
    const int h = idx / 4104, j = idx - h * 4104;
    const int d = j - 3;
    float val = 0.f;
    if (d >= 0 && d < 4096) {
      int b;
      if (d < 16) {
        b = d;
      } else {
        const int T[15] = {23, 32, 46, 64, 91, 128, 182, 256, 363, 512,
                           725, 1024, 1449, 2048, 2897};
        int m = 0;
#pragma unroll
        for (int i = 0; i < 15; ++i) m += (d >= T[i]);
        b = 16 + m;
      }
      val = rpe[b * 16 + h] * 1.4426950408889634f;
    }
    bt[idx] = val;
  }
}

// ---------------- GEMM: C[4096,1024] = A @ W + bias (Wt = W^T, both bf16) ----------
// 128xBN tile, BK=64, 4 waves (2x2). 2-phase double-buffered schedule:
// STAGE(next) issued BEFORE ds_read+MFMA(cur); one __syncthreads per k-step.
// global_load_lds width-16: linear LDS dest + inverse-swizzled source; swizzled read.
template <typename OT, int BN>
__device__ __forceinline__ void gemm_body(const bf16* __restrict__ A,
                                          const bf16* __restrict__ Wt,
                                          const float* __restrict__ bias,
                                          OT* __restrict__ C, bool vt,
                                          bf16* As, bf16* Bs)
{
  constexpr int NF = BN / 32;            // N-frags per wave
  constexpr int ABYTES = 128 * 128;      // 128 rows x 128B
  constexpr int BBYTES = BN * 128;
  const int tid = threadIdx.x;
  const int lane = tid & 63, wid = tid >> 6;
  const int l15 = lane & 15, lg = lane >> 4;
  const int wr = wid >> 1, wc = wid & 1;
  const int m0 = blockIdx.x * 128, n0 = blockIdx.y * BN;

  f32x4 acc[4][NF];
#pragma unroll
  for (int i = 0; i < 4; ++i)
#pragma unroll
    for (int j = 0; j < NF; ++j) acc[i][j] = (f32x4){0.f, 0.f, 0.f, 0.f};

  auto STAGE = [&](int buf, int kt) {
    const int k0 = kt * 64;
#pragma unroll
    for (int it = 0; it < 4; ++it) {
      const int o = tid * 16 + it * 4096;
      const int row = o >> 7;
      const int sl = ((o >> 4) & 7) ^ (row & 7);
      g2l16(A + (size_t)(m0 + row) * 1024 + k0 + sl * 8,
            (char*)As + buf * ABYTES + wid * 1024 + it * 4096);
    }
#pragma unroll
    for (int it = 0; it < BN / 32; ++it) {
      const int o = tid * 16 + it * 4096;
      const int row = o >> 7;
      const int sl = ((o >> 4) & 7) ^ (row & 7);
      g2l16(Wt + (size_t)(n0 + row) * 1024 + k0 + sl * 8,
            (char*)Bs + buf * BBYTES + wid * 1024 + it * 4096);
    }
  };

  STAGE(0, 0);
  __syncthreads();   // drains vmcnt; tile 0 ready
  int cur = 0;

#pragma unroll 1
  for (int kt = 0; kt < 16; ++kt) {
    if (kt + 1 < 16) STAGE(cur ^ 1, kt + 1);   // issue next-tile loads first

    const char* Ab = (const char*)As + cur * ABYTES;
    const char* Bb = (const char*)Bs + cur * BBYTES;
    bf16x8 af[2][4], bfr[2][NF];
#pragma unroll
    for (int ks = 0; ks < 2; ++ks) {
      const int s8 = ks * 4 + lg;
#pragma unroll
      for (int f = 0; f < 4; ++f) {
        const int ra_ = wr * 64 + f * 16 + l15;
        af[ks][f] = *(const bf16x8*)(Ab + ra_ * 128 + ((s8 ^ (ra_ & 7)) << 4));
      }
#pragma unroll
      for (int f = 0; f < NF; ++f) {
        const int rb_ = wc * (BN / 2) + f * 16 + l15;
        bfr[ks][f] = *(const bf16x8*)(Bb + rb_ * 128 + ((s8 ^ (rb_ & 7)) << 4));
      }
    }
    __builtin_amdgcn_s_setprio(1);
#pragma unroll
    for (int ks = 0; ks < 2; ++ks)
#pragma unroll
      for (int mf = 0; mf < 4; ++mf)
#pragma unroll
        for (int nf = 0; nf < NF; ++nf)
          acc[mf][nf] = __builtin_amdgcn_mfma_f32_16x16x32_bf16(
              af[ks][mf], bfr[ks][nf], acc[mf][nf], 0, 0, 0);
    __builtin_amdgcn_s_setprio(0);
    __syncthreads();   // drains vmcnt: next tile landed; cur-buffer reads done
    cur ^= 1;
  }

#pragma unroll
  for (int nf = 0; nf < NF; ++nf) {
    const int col = n0 + wc * (BN / 2) + nf * 16 + l15;
    const float bv = bias[col];
#pragma unroll
    for (int mf = 0; mf < 4; ++mf) {
      const int rowb = m0 + wr * 64 + mf * 16 + lg * 4;
#pragma unroll
      for (int r = 0; r < 4; ++r) {
        const float val = acc[mf][nf][r] + bv;
        if constexpr (sizeof(OT) == 2) {
          if (vt)   // V stored transposed per head: C[h][d][row]
            ((bf16*)C)[((size_t)(col >> 6) << 18) + ((size_t)(col & 63) << 12) + rowb + r] =
                __float2bfloat16(val);
          else
            ((bf16*)C)[(size_t)(rowb + r) * 1024 + col] = __float2bfloat16(val);
        } else {
          ((float*)C)[(size_t)(rowb + r) * 1024 + col] = val;
        }
      }
    }
  }
}

__global__ __launch_bounds__(256)
void gemm_qkv(const bf16* __restrict__ xq, const bf16* __restrict__ xk,
              const bf16* __restrict__ xv,
              const bf16* __restrict__ wqt, const bf16* __restrict__ wkt,
              const bf16* __restrict__ wvt,
              const float* __restrict__ bq, const float* __restrict__ bk,
              const float* __restrict__ bv,
              bf16* __restrict__ Q, bf16* __restrict__ K, bf16* __restrict__ VtG)
{
  __shared__ bf16 As[2 * 128 * 64], Bs[2 * 128 * 64];
  const int z = blockIdx.z;
  gemm_body<bf16, 128>(z == 0 ? xq : z == 1 ? xk : xv,
                       z == 0 ? wqt : z == 1 ? wkt : wvt,
                       z == 0 ? bq : z == 1 ? bk : bv,
                       z == 0 ? Q : z == 1 ? K : VtG, z == 2, As, Bs);
}

__global__ __launch_bounds__(256)
void gemm_out_k(const bf16* __restrict__ A, const bf16* __restrict__ Wt,
                const float* __restrict__ bias, float* __restrict__ C)
{
  __shared__ bf16 As[2 * 128 * 64], Bs[2 * 64 * 64];
  gemm_body<float, 64>(A, Wt, bias, C, false, As, Bs);
}

// ---------------- causal flash attention + T5 bias (swapped QK^T) ----------------
// grid 1024; bid -> (h = bid&15, qt = 63 - bid>>4). 4 waves x 16 q-rows, KV tile 64.
// log2-domain softmax, defer-max (THR=11), vectorized bias loads, setprio on MFMA.
__global__ __launch_bounds__(256)
void attn_kernel(const bf16* __restrict__ Qb, const bf16* __restrict__ Kb,
                 const bf16* __restrict__ VtG, const float* __restrict__ bias_tab,
                 bf16* __restrict__ Ob)
{
  __shared__ bf16 Ks[64 * 64];
  __shared__ bf16 Vs[64 * 64];
  __shared__ bf16 Pl[4][16 * 76];

  const int tid = threadIdx.x;
  const int lane = tid & 63, wid = tid >> 6;
  const int l15 = lane & 15, lg = lane >> 4;
  const int bid = blockIdx.x;
  const int h  = bid & 15;
  const int qt = 63 - (bid >> 4);
  const int nt = qt + 1;
  const int qw = qt * 64 + wid * 16;
  const int q_abs = qw + l15;
  const float C1 = 0.125f * 1.4426950408889634f;   // scale * log2(e)

  const bf16* Kh = Kb + h * 64;
  const bf16* Vh = VtG + ((size_t)h << 18);
  const float* bh = bias_tab + h * 4104 + 3;
  bf16* pw = &Pl[wid][0];

  const int kr0 = tid >> 3, ks0_ = tid & 7;
  const int kr1 = (tid + 256) >> 3, ks1_ = tid & 7;

  bf16x8 qf[2];
  {
    const bf16* qp = Qb + (size_t)q_abs * 1024 + h * 64 + lg * 8;
    qf[0] = *(const bf16x8*)qp;
    qf[1] = *(const bf16x8*)(qp + 32);
  }

  f32x4 o_acc[4];
#pragma unroll
  for (int nf = 0; nf < 4; ++nf) o_acc[nf] = (f32x4){0.f, 0.f, 0.f, 0.f};
  float m_run = -1e30f, l_run = 0.f;

  // prologue: load tile 0 into regs
  bf16x8 rk0 = *(const bf16x8*)(Kh + (size_t)kr0 * 1024 + ks0_ * 8);
  bf16x8 rk1 = *(const bf16x8*)(Kh + (size_t)kr1 * 1024 + ks1_ * 8);
  bf16x8 rv0 = *(const bf16x8*)(Vh + (size_t)kr0 * 4096 + ks0_ * 8);
  bf16x8 rv1 = *(const bf16x8*)(Vh + (size_t)kr1 * 4096 + ks1_ * 8);

#pragma unroll 1
  for (int t = 0; t < nt; ++t) {
    const int k0 = t * 64;
    __syncthreads();
    {
      const int o0 = kr0 * 128 + ((ks0_ ^ (kr0 & 7)) << 4);
      const int o1 = kr1 * 128 + ((ks1_ ^ (kr1 & 7)) << 4);
      *(bf16x8*)((char*)Ks + o0) = rk0;
      *(bf16x8*)((char*)Ks + o1) = rk1;
      *(bf16x8*)((char*)Vs + o0) = rv0;
      *(bf16x8*)((char*)Vs + o1) = rv1;
    }
    __syncthreads();
    if (t + 1 < nt) {   // T14: issue next tile's loads early
      const int k1 = k0 + 64;
      rk0 = *(const bf16x8*)(Kh + (size_t)(k1 + kr0) * 1024 + ks0_ * 8);
      rk1 = *(const bf16x8*)(Kh + (size_t)(k1 + kr1) * 1024 + ks1_ * 8);
      rv0 = *(const bf16x8*)(Vh + (size_t)kr0 * 4096 + k1 + ks0_ * 8);
      rv1 = *(const bf16x8*)(Vh + (size_t)kr1 * 4096 + k1 + ks1_ * 8);
    }

    // S^T = K . Q^T : lane holds S[q = q_abs][k = k0 + kf*16 + lg*4 + r]
    f32x4 st[4];
#pragma unroll
    for (int kf = 0; kf < 4; ++kf) st[kf] = (f32x4){0.f, 0.f, 0.f, 0.f};
    __builtin_amdgcn_s_setprio(1);
#pragma unroll
    for (int kf = 0; kf < 4; ++kf) {
      const int row = kf * 16 + l15;
#pragma unroll
      for (int ks = 0; ks < 2; ++ks) {
        const int s8 = ks * 4 + lg;
        bf16x8 kfr = *(const bf16x8*)((const char*)Ks + row * 128 + ((s8 ^ (row & 7)) << 4));
        st[kf] = __builtin_amdgcn_mfma_f32_16x16x32_bf16(kfr, qf[ks], st[kf], 0, 0, 0);
      }
    }
    __builtin_amdgcn_s_setprio(0);

    // bias (vectorized, log2-domain) + mask + per-row max
    float mt = -1e30f;
#pragma unroll
    for (int kf = 0; kf < 4; ++kf) {
      const int dtop = q_abs - (k0 + kf * 16 + lg * 4);
      f32x4a b4 = (f32x4a){0.f, 0.f, 0.f, 0.f};
      if (dtop >= 0) b4 = *(const f32x4a*)(bh + dtop - 3);
#pragma unroll
      for (int r = 0; r < 4; ++r) {
        const float bb = (dtop - r >= 0) ? b4[3 - r] : -1e30f;
        const float sv = st[kf][r] * C1 + bb;
        st[kf][r] = sv;
        mt = fmaxf(mt, sv);
      }
    }
    mt = fmaxf(mt, __shfl_xor(mt, 16, 64));
    mt = fmaxf(mt, __shfl_xor(mt, 32, 64));

    // T13 defer-max: only rescale when tile max beats running max by >11 (log2)
    if (__any(mt > m_run + 11.0f)) {
      const float newm = fmaxf(m_run, mt);
      const float sc = (m_run > -1e29f) ? exp2f(m_run - newm) : 0.f;
      m_run = newm;
      float scr[4];
#pragma unroll
      for (int r = 0; r < 4; ++r) scr[r] = __shfl(sc, lg * 4 + r, 64);
#pragma unroll
      for (int nf = 0; nf < 4; ++nf)
#pragma unroll
        for (int r = 0; r < 4; ++r) o_acc[nf][r] *= scr[r];
      l_run *= sc;
    }

    float rs = 0.f;
    bf16x4 pk[4];
#pragma unroll
    for (int kf = 0; kf < 4; ++kf)
#pragma unroll
      for (int r = 0; r < 4; ++r) {
        const float p = (st[kf][r] > -1e29f) ? exp2f(st[kf][r] - m_run) : 0.f;
        ((bf16*)&pk[kf])[r] = __float2bfloat16(p);
        rs += p;
      }
    rs += __shfl_xor(rs, 16, 64);
    rs += __shfl_xor(rs, 32, 64);
    l_run += rs;

    // P strip: lane writes its 4 consecutive k per kf (b64)
#pragma unroll
    for (int kf = 0; kf < 4; ++kf)
      *(bf16x4*)&pw[l15 * 76 + kf * 16 + lg * 4] = pk[kf];

    // PV: A = P (q rows), B = V^T-staged (d cols, k contiguous)
    bf16x8 pf[2];
#pragma unroll
    for (int ks2 = 0; ks2 < 2; ++ks2)
      pf[ks2] = *(const bf16x8*)&pw[l15 * 76 + ks2 * 32 + lg * 8];
    __builtin_amdgcn_s_setprio(1);
#pragma unroll
    for (int ks2 = 0; ks2 < 2; ++ks2)
#pragma unroll
      for (int nf = 0; nf < 4; ++nf) {
        const int row = nf * 16 + l15;
        const int s8 = ks2 * 4 + lg;
        bf16x8 vfr = *(const bf16x8*)((const char*)Vs + row * 128 + ((s8 ^ (row & 7)) << 4));
        o_acc[nf] = __builtin_amdgcn_mfma_f32_16x16x32_bf16(pf[ks2], vfr, o_acc[nf], 0, 0, 0);
      }
    __builtin_amdgcn_s_setprio(0);
  }

  // epilogue: O / l, store [S, H*64]
  const float linv = 1.f / l_run;
  float lr[4];
#pragma unroll
  for (int r = 0; r < 4; ++r) lr[r] = __shfl(linv, lg * 4 + r, 64);
#pragma unroll
  for (int nf = 0; nf < 4; ++nf)
#pragma unroll
    for (int r = 0; r < 4; ++r) {
      const int row = qw + lg * 4 + r;
      Ob[(size_t)row * 1024 + h * 64 + nf * 16 + l15] =
          __float2bfloat16(o_acc[nf][r] * lr[r]);
    }
}

// ---------------- launch ----------------
extern "C" void kernel_launch(void* const* d_in, const int* in_sizes, int n_in,
                              void* d_out, int out_size, void* d_ws, size_t ws_size,
                              hipStream_t stream) {
  (void)in_sizes; (void)n_in; (void)out_size; (void)ws_size;
  const float* q   = (const float*)d_in[0];
  const float* k   = (const float*)d_in[1];
  const float* v   = (const float*)d_in[2];
  // d_in[3] = causal mask, deterministic -> ignored
  const float* Wq  = (const float*)d_in[4];
  const float* bq  = (const float*)d_in[5];
  const float* Wk  = (const float*)d_in[6];
  const float* bk  = (const float*)d_in[7];
  const float* Wv  = (const float*)d_in[8];
  const float* bv  = (const float*)d_in[9];
  const float* Wo  = (const float*)d_in[10];
  const float* bo  = (const float*)d_in[11];
  const float* rpe = (const float*)d_in[12];
  float* out = (float*)d_out;

  char* ws = (char*)d_ws;
  bf16* WqT   = (bf16*)(ws + (size_t)0);
  bf16* WkT   = (bf16*)(ws + ((size_t)2  << 20));
  bf16* WvT   = (bf16*)(ws + ((size_t)4  << 20));
  bf16* WoT   = (bf16*)(ws + ((size_t)6  << 20));
  bf16* xq_bf = (bf16*)(ws + ((size_t)8  << 20));
  bf16* xk_bf = (bf16*)(ws + ((size_t)16 << 20));
  bf16* xv_bf = (bf16*)(ws + ((size_t)24 << 20));
  bf16* Qb    = (bf16*)(ws + ((size_t)32 << 20));
  bf16* Kb    = (bf16*)(ws + ((size_t)40 << 20));
  bf16* VtG   = (bf16*)(ws + ((size_t)48 << 20));   // [16][64][4096]
  float* bias_tab = (float*)(ws + ((size_t)56 << 20));
  bf16* Ob    = xq_bf;   // xq_bf dead after gemm_qkv; reuse for attn output

  prep<<<dim3(2048, 1, 8), 256, 0, stream>>>(q, k, v, xq_bf, xk_bf, xv_bf,
                                             Wq, Wk, Wv, Wo, WqT, WkT, WvT, WoT,
                                             rpe, bias_tab);
  gemm_qkv<<<dim3(32, 8, 3), 256, 0, stream>>>(xq_bf, xk_bf, xv_bf, WqT, WkT, WvT,
                                               bq, bk, bv, Qb, Kb, VtG);
  attn_kernel<<<dim3(1024), 256, 0, stream>>>(Qb, Kb, VtG, bias_tab, Ob);
  gemm_out_k<<<dim3(32, 16), 256, 0, stream>>>(Ob, WoT, bo, out);
}